// Round 17
// baseline (93.505 us; speedup 1.0000x reference)
//
#include <hip/hip_runtime.h>
#include <hip/hip_bf16.h>

// CapsNet dynamic routing — v11: LDS-free u_hat producer + bf16 u_hat.
// x: [B=32, N=4096, Din=8], W: [N=4096, C=10, Din=8, D=16], out: [B,C,D] f32.
// Algebra (b0=0): iter0 w=1/C; iter1 logits=u_hat.v0; iter2 logits=u_hat.(v0+v1).
// r16 evidence: streaming kernels (no LDS) hit 4.7-5.6 TB/s; every LDS-staged
// skeleton stuck at 25-45us (VALU 13%, HBM 30%, Occ 30% - nothing saturated).
// v11: A reads W straight from global (no LDS/barriers), u_hat stored bf16
// (halves A writes + B reads; error budget ~1e-3 vs 1.5e-2 threshold).

#define BB 32
#define NN 4096
#define CC 10
#define DIN 8
#define DD 16
#define NCHUNK 8
#define NCHUNKS_TOTAL (NN / NCHUNK)   // 512
#define TPB 512
#define SOUT (BB * CC * DD)           // 5120
#define UHATE ((size_t)BB * NN * CC * DD)   // 20,971,520 elements

// ---- DPP row-of-16 sum (d-reduce), all lanes get the total ----
template<int CTRL>
__device__ __forceinline__ float dpp_mov(float x) {
    return __int_as_float(__builtin_amdgcn_update_dpp(
        0, __float_as_int(x), CTRL, 0xF, 0xF, true));
}
__device__ __forceinline__ float row_sum16(float x) {
    x += dpp_mov<0xB1>(x);    // quad_perm d^1
    x += dpp_mov<0x4E>(x);    // quad_perm d^2
    x += dpp_mov<0x124>(x);   // row_ror:4
    x += dpp_mov<0x128>(x);   // row_ror:8
    return x;
}

__device__ __forceinline__ float bf2f(unsigned short u) {
    return __uint_as_float((unsigned int)u << 16);
}

// ========== Kernel A: u_hat (bf16) + uniform pass0, NO LDS ==========
// 8 waves; wave bq handles b=bq*4..bq*4+3. Lane: cq=lane>>4, d=lane&15; c=cq+4r.
// W fragment read per (r,i) as lane-indexed dwords: addr = n*5120+c*128+i*16+d
// -> wave covers 4 x 64B segments, coalesced; fragment reused for 4 b's in regs.
__global__ __launch_bounds__(TPB) void caps_uhat_pass0(
    const float* __restrict__ xg,
    const float* __restrict__ Wg,
    __hip_bfloat16* __restrict__ uhat,  // [B,N,C*D] bf16
    float* __restrict__ part)           // [512][SOUT]
{
    const int t    = threadIdx.x;
    const int lane = t & 63;
    const int bqu  = __builtin_amdgcn_readfirstlane(t >> 6);
    const int cq   = lane >> 4;
    const int d    = lane & 15;

    float acc[4][3];
    #pragma unroll
    for (int bb = 0; bb < 4; ++bb)
        #pragma unroll
        for (int r = 0; r < 3; ++r) acc[bb][r] = 0.f;

    const int n0 = blockIdx.x * NCHUNK;

    #pragma unroll 1   // keep live ranges small (r11 lesson)
    for (int j = 0; j < NCHUNK; ++j) {
        const int n = n0 + j;

        // u rows: wave-uniform -> scalar loads
        float ub[4][8];
        #pragma unroll
        for (int bb = 0; bb < 4; ++bb) {
            const float* up = xg + ((size_t)(bqu * 4 + bb) * NN + n) * DIN;
            #pragma unroll
            for (int i = 0; i < 8; ++i) ub[bb][i] = up[i];
        }

        #pragma unroll
        for (int r = 0; r < 3; ++r) {
            const int c = cq + 4 * r;
            float wf[8];
            if (c < CC) {
                const float* wp = Wg + (size_t)n * (CC * DIN * DD) + c * (DIN * DD) + d;
                #pragma unroll
                for (int i = 0; i < 8; ++i) wf[i] = wp[i * DD];   // coalesced 4x64B
            } else {
                #pragma unroll
                for (int i = 0; i < 8; ++i) wf[i] = 0.f;
            }
            #pragma unroll
            for (int bb = 0; bb < 4; ++bb) {
                const int b = bqu * 4 + bb;
                float s = 0.f;
                #pragma unroll
                for (int i = 0; i < 8; ++i) s = fmaf(ub[bb][i], wf[i], s);
                if (c < CC)
                    uhat[((size_t)b * NN + n) * (CC * DD) + lane + 64 * r] =
                        __float2bfloat16(s);
                acc[bb][r] += s;
            }
        }
    }

    float* dst = part + (size_t)blockIdx.x * SOUT;
    #pragma unroll
    for (int bb = 0; bb < 4; ++bb) {
        int b = bqu * 4 + bb;
        #pragma unroll
        for (int r = 0; r < 3; ++r) {
            int c = cq + 4 * r;
            if (c < CC) dst[(b * CC + c) * DD + d] = acc[bb][r] * (1.0f / CC);
        }
    }
}

// ========== Kernel B: routed pass streaming bf16 u_hat (no LDS) ==========
__global__ __launch_bounds__(TPB) void caps_routed(
    const __hip_bfloat16* __restrict__ uhat,  // [B,N,C*D] bf16
    const float* __restrict__ vprev,          // [B,C,D]
    float* __restrict__ part)                 // [512][SOUT]
{
    const int t    = threadIdx.x;
    const int lane = t & 63;
    const int bqu  = __builtin_amdgcn_readfirstlane(t >> 6);
    const int cq   = lane >> 4;
    const int d    = lane & 15;

    float vv[4][3];
    #pragma unroll
    for (int bb = 0; bb < 4; ++bb) {
        int b = bqu * 4 + bb;
        #pragma unroll
        for (int r = 0; r < 3; ++r) {
            int c = cq + 4 * r;
            vv[bb][r] = (c < CC) ? vprev[(b * CC + c) * DD + d] : 0.f;
        }
    }

    float acc[4][3];
    #pragma unroll
    for (int bb = 0; bb < 4; ++bb)
        #pragma unroll
        for (int r = 0; r < 3; ++r) acc[bb][r] = 0.f;

    const int n0 = blockIdx.x * NCHUNK;

    #pragma unroll 1
    for (int j = 0; j < NCHUNK; ++j) {
        const int n = n0 + j;
        float uh[4][3];
        #pragma unroll
        for (int bb = 0; bb < 4; ++bb) {
            const __hip_bfloat16* base =
                uhat + ((size_t)(bqu * 4 + bb) * NN + n) * (CC * DD);
            #pragma unroll
            for (int r = 0; r < 3; ++r) {
                int c = cq + 4 * r;
                uh[bb][r] = (c < CC) ? __bfloat162float(base[lane + 64 * r]) : 0.f;
            }
        }
        #pragma unroll
        for (int bb = 0; bb < 4; ++bb) {
            float dot0 = row_sum16(uh[bb][0] * vv[bb][0]);
            float dot1 = row_sum16(uh[bb][1] * vv[bb][1]);
            float dot2 = row_sum16(uh[bb][2] * vv[bb][2]);
            // no max-subtract: |dot| bounded (~2), exp safe (r12-verified)
            float e0 = __expf(dot0);
            float e1 = __expf(dot1);
            float e2 = (cq < 2) ? __expf(dot2) : 0.f;
            float den = e0 + e1 + e2;
            den += __shfl_xor(den, 16, 64);
            den += __shfl_xor(den, 32, 64);
            float inv = __builtin_amdgcn_rcpf(den);
            acc[bb][0] = fmaf(e0 * inv, uh[bb][0], acc[bb][0]);
            acc[bb][1] = fmaf(e1 * inv, uh[bb][1], acc[bb][1]);
            acc[bb][2] = fmaf(e2 * inv, uh[bb][2], acc[bb][2]);
        }
    }

    float* dst = part + (size_t)blockIdx.x * SOUT;
    #pragma unroll
    for (int bb = 0; bb < 4; ++bb) {
        int b = bqu * 4 + bb;
        #pragma unroll
        for (int r = 0; r < 3; ++r) {
            int c = cq + 4 * r;
            if (c < CC) dst[(b * CC + c) * DD + d] = acc[bb][r];
        }
    }
}

// ======== Fallback (r14-proven): LDS recompute pass ========
template<int UNIFORM, int PARTIALS>
__global__ __launch_bounds__(TPB) void caps_pass(
    const float* __restrict__ xg,
    const float* __restrict__ Wg,
    const float* __restrict__ vprev,
    float* __restrict__ outp)
{
    __shared__ float Wl[NCHUNK * CC * DIN * DD];

    const int t    = threadIdx.x;
    const int lane = t & 63;
    const int bqu  = __builtin_amdgcn_readfirstlane(t >> 6);
    const int cq   = lane >> 4;
    const int d    = lane & 15;

    float vv[4][3];
    if (!UNIFORM) {
        #pragma unroll
        for (int bb = 0; bb < 4; ++bb) {
            int b = bqu * 4 + bb;
            #pragma unroll
            for (int r = 0; r < 3; ++r) {
                int c = cq + 4 * r;
                vv[bb][r] = (c < CC) ? vprev[(b * CC + c) * DD + d] : 0.f;
            }
        }
    }

    float acc[4][3];
    #pragma unroll
    for (int bb = 0; bb < 4; ++bb)
        #pragma unroll
        for (int r = 0; r < 3; ++r) acc[bb][r] = 0.f;

    for (int chunk = blockIdx.x; chunk < NCHUNKS_TOTAL; chunk += gridDim.x) {
        const int n0 = chunk * NCHUNK;
        {
            const float4* WgV = (const float4*)Wg;
            #pragma unroll
            for (int wi = 0; wi < 5; ++wi) {
                int m4 = t + wi * TPB;
                int j = m4 / 320, q = m4 - j * 320;
                int c = q >> 5, i = (q & 31) >> 2, d0 = (q & 3) << 2;
                float4 v = WgV[(size_t)n0 * 320 + m4];
                const float* vf = (const float*)&v;
                float* plane = Wl + j * 1280;
                int h = i >> 2, wd = i & 3;
                #pragma unroll
                for (int k = 0; k < 4; ++k) {
                    int R = c * DD + d0 + k;
                    int U = (R * 2 + h) ^ ((R >> 2) & 7);
                    plane[U * 4 + wd] = vf[k];
                }
            }
        }
        __syncthreads();

        #pragma unroll 1
        for (int j = 0; j < NCHUNK; ++j) {
            const float4* planeV = (const float4*)(Wl + j * 1280);
            float ub[4][8];
            #pragma unroll
            for (int bb = 0; bb < 4; ++bb) {
                const float* up = xg + ((size_t)(bqu * 4 + bb) * NN + n0 + j) * DIN;
                #pragma unroll
                for (int i = 0; i < 8; ++i) ub[bb][i] = up[i];
            }
            float uh[4][3];
            #pragma unroll
            for (int r = 0; r < 3; ++r) {
                int c = cq + 4 * r;
                float w0=0,w1=0,w2=0,w3=0,w4=0,w5=0,w6=0,w7=0;
                if (c < CC) {
                    int R = c * DD + d, sw = (R >> 2) & 7;
                    float4 a0 = planeV[(R * 2) ^ sw];
                    float4 a1 = planeV[(R * 2 + 1) ^ sw];
                    w0=a0.x; w1=a0.y; w2=a0.z; w3=a0.w;
                    w4=a1.x; w5=a1.y; w6=a1.z; w7=a1.w;
                }
                #pragma unroll
                for (int bb = 0; bb < 4; ++bb) {
                    float s = 0.f;
                    s = fmaf(ub[bb][0], w0, s); s = fmaf(ub[bb][1], w1, s);
                    s = fmaf(ub[bb][2], w2, s); s = fmaf(ub[bb][3], w3, s);
                    s = fmaf(ub[bb][4], w4, s); s = fmaf(ub[bb][5], w5, s);
                    s = fmaf(ub[bb][6], w6, s); s = fmaf(ub[bb][7], w7, s);
                    uh[bb][r] = s;
                }
            }
            #pragma unroll
            for (int bb = 0; bb < 4; ++bb) {
                float w0, w1, w2;
                if (UNIFORM) { w0 = w1 = w2 = 1.0f / CC; }
                else {
                    float dot0 = row_sum16(uh[bb][0] * vv[bb][0]);
                    float dot1 = row_sum16(uh[bb][1] * vv[bb][1]);
                    float dot2 = row_sum16(uh[bb][2] * vv[bb][2]);
                    float e0 = __expf(dot0), e1 = __expf(dot1);
                    float e2 = (cq < 2) ? __expf(dot2) : 0.f;
                    float den = e0 + e1 + e2;
                    den += __shfl_xor(den, 16, 64);
                    den += __shfl_xor(den, 32, 64);
                    float inv = __builtin_amdgcn_rcpf(den);
                    w0 = e0 * inv; w1 = e1 * inv; w2 = e2 * inv;
                }
                acc[bb][0] = fmaf(w0, uh[bb][0], acc[bb][0]);
                acc[bb][1] = fmaf(w1, uh[bb][1], acc[bb][1]);
                acc[bb][2] = fmaf(w2, uh[bb][2], acc[bb][2]);
            }
        }
        __syncthreads();
    }

    #pragma unroll
    for (int bb = 0; bb < 4; ++bb) {
        int b = bqu * 4 + bb;
        #pragma unroll
        for (int r = 0; r < 3; ++r) {
            int c = cq + 4 * r;
            if (c < CC) {
                if (PARTIALS) (outp + (size_t)blockIdx.x * SOUT)[(b * CC + c) * DD + d] = acc[bb][r];
                else atomicAdd(&outp[(b * CC + c) * DD + d], acc[bb][r]);
            }
        }
    }
}

// Fused cross-block reduce + squash over G partial slices.
// MODE 0: vsum=v ; 1: vsum+=v ; 2: outF=v
template<int MODE>
__global__ __launch_bounds__(256) void caps_reduce(
    const float* __restrict__ part, int G,
    float* __restrict__ vsum, float* __restrict__ outF)
{
    __shared__ float red[256];
    const int row = blockIdx.x;
    const int t = threadIdx.x;
    const int d = t & 15, ks = t >> 4;
    const int per = G >> 4;
    const float* p = part + row * DD + d;
    float s = 0.f;
    for (int kk = 0; kk < per; ++kk)
        s += p[(size_t)(ks * per + kk) * SOUT];
    red[t] = s;
    __syncthreads();
    if (t < 16) {
        float sd = 0.f;
        #pragma unroll
        for (int k2 = 0; k2 < 16; ++k2) sd += red[k2 * 16 + t];
        float s2 = sd * sd;
        #pragma unroll
        for (int m = 1; m < 16; m <<= 1) s2 += __shfl_xor(s2, m, 64);
        float f = s2 / ((1.f + s2) * sqrtf(s2 + 1e-7f));
        float v = f * sd;
        int idx = row * DD + t;
        if (MODE == 0) vsum[idx] = v;
        if (MODE == 1) vsum[idx] += v;
        if (MODE == 2) outF[idx] = v;
    }
}

// Atomic-fallback squash.
template<int MODE>
__global__ __launch_bounds__(512) void caps_squash(
    const float* __restrict__ sIn, float* __restrict__ vsum,
    float* __restrict__ outF)
{
    int r = blockIdx.x * blockDim.x + threadIdx.x;
    if (r >= BB * CC) return;
    const float* p = sIn + (size_t)r * DD;
    float sv[DD]; float s2 = 0.f;
    #pragma unroll
    for (int d = 0; d < DD; ++d) { sv[d] = p[d]; s2 = fmaf(sv[d], sv[d], s2); }
    float f = s2 / ((1.f + s2) * sqrtf(s2 + 1e-7f));
    #pragma unroll
    for (int d = 0; d < DD; ++d) {
        float v = f * sv[d];
        int idx = r * DD + d;
        if (MODE == 0) vsum[idx] = v;
        if (MODE == 1) vsum[idx] += v;
        if (MODE == 2) outF[idx] = v;
    }
}

extern "C" void kernel_launch(void* const* d_in, const int* in_sizes, int n_in,
                              void* d_out, int out_size, void* d_ws, size_t ws_size,
                              hipStream_t stream) {
    const float* x; const float* Wt;
    if (in_sizes[0] == BB * NN * DIN) { x = (const float*)d_in[0]; Wt = (const float*)d_in[1]; }
    else                              { Wt = (const float*)d_in[0]; x = (const float*)d_in[1]; }
    float* out = (float*)d_out;
    float* ws = (float*)d_ws;

    const int G = 512;
    // uhat bf16 (UHATE * 2 bytes) + partials + vsum
    const size_t uhat_floats = UHATE / 2;   // bf16 elements packed in float units
    const size_t need = UHATE * sizeof(__hip_bfloat16)
                      + (size_t)(G + 1) * SOUT * sizeof(float);

    if (ws_size >= need) {
        __hip_bfloat16* uhat = (__hip_bfloat16*)ws;
        float* part = ws + uhat_floats;
        float* vsum = part + (size_t)G * SOUT;
        caps_uhat_pass0<<<G, TPB, 0, stream>>>(x, Wt, uhat, part);
        caps_reduce<0><<<BB*CC, 256, 0, stream>>>(part, G, vsum, nullptr);
        caps_routed<<<G, TPB, 0, stream>>>(uhat, vsum, part);
        caps_reduce<1><<<BB*CC, 256, 0, stream>>>(part, G, vsum, nullptr);
        caps_routed<<<G, TPB, 0, stream>>>(uhat, vsum, part);
        caps_reduce<2><<<BB*CC, 256, 0, stream>>>(part, G, vsum, out);
    } else {
        // r14-proven fallback
        const size_t wsf = ws_size / sizeof(float);
        int Gf = 0;
        const int cands[5] = {512, 256, 128, 64, 32};
        for (int ci = 0; ci < 5; ++ci)
            if (wsf >= (size_t)(cands[ci] + 1) * SOUT) { Gf = cands[ci]; break; }
        if (Gf > 0) {
            float* part = ws;
            float* vsum = ws + (size_t)Gf * SOUT;
            caps_pass<1,1><<<Gf, TPB, 0, stream>>>(x, Wt, nullptr, part);
            caps_reduce<0><<<BB*CC, 256, 0, stream>>>(part, Gf, vsum, nullptr);
            caps_pass<0,1><<<Gf, TPB, 0, stream>>>(x, Wt, vsum, part);
            caps_reduce<1><<<BB*CC, 256, 0, stream>>>(part, Gf, vsum, nullptr);
            caps_pass<0,1><<<Gf, TPB, 0, stream>>>(x, Wt, vsum, part);
            caps_reduce<2><<<BB*CC, 256, 0, stream>>>(part, Gf, vsum, out);
        } else {
            float* sAcc = ws;
            float* vsum = ws + SOUT;
            hipMemsetAsync(sAcc, 0, SOUT * sizeof(float), stream);
            caps_pass<1,0><<<64, TPB, 0, stream>>>(x, Wt, nullptr, sAcc);
            caps_squash<0><<<1, 512, 0, stream>>>(sAcc, vsum, nullptr);
            hipMemsetAsync(sAcc, 0, SOUT * sizeof(float), stream);
            caps_pass<0,0><<<64, TPB, 0, stream>>>(x, Wt, vsum, sAcc);
            caps_squash<1><<<1, 512, 0, stream>>>(sAcc, vsum, nullptr);
            hipMemsetAsync(sAcc, 0, SOUT * sizeof(float), stream);
            caps_pass<0,0><<<64, TPB, 0, stream>>>(x, Wt, vsum, sAcc);
            caps_squash<2><<<1, 512, 0, stream>>>(sAcc, nullptr, out);
        }
    }
}

// Round 18
// 80.999 us; speedup vs baseline: 1.1544x; 1.1544x over previous
//
#include <hip/hip_runtime.h>
#include <hip/hip_bf16.h>

// CapsNet dynamic routing — v12: v10 base + A-occupancy (NCHUNK=4,G=1024)
// + fast reduce (TPB=1024, stride-64 slice loop).
// x: [B=32, N=4096, Din=8], W: [N=4096, C=10, Din=8, D=16], out: [B,C,D] f32.
// Algebra (b0=0): iter0 w=1/C; iter1 logits=u_hat.v0; iter2 logits=u_hat.(v0+v1).
// Evidence: v10 measured A=41us (Occ 30%, grid-limited waves), B~16 (near-BW),
// r15 showed NCHUNK=4 pass <=41 but G=1024 reduce was the regression (strided
// 64B gather, latency-bound). v12 fixes both: more blocks for A, more waves +
// shorter load chains for reduce. u_hat stays f32 (bf16 gained nothing, r17).

#define BB 32
#define NN 4096
#define CC 10
#define DIN 8
#define DD 16
#define TPB 512
#define SOUT (BB * CC * DD)           // 5120
#define UHATF ((size_t)BB * NN * CC * DD)   // 20,971,520 floats (84MB)

// A: 4-n chunks, one per block
#define NCHUNK_A 4
#define GA (NN / NCHUNK_A)            // 1024
// B: 8-n chunks, one per block
#define NCHUNK_B 8
#define GB (NN / NCHUNK_B)            // 512

// ---- DPP row-of-16 sum (d-reduce), all lanes get the total ----
template<int CTRL>
__device__ __forceinline__ float dpp_mov(float x) {
    return __int_as_float(__builtin_amdgcn_update_dpp(
        0, __float_as_int(x), CTRL, 0xF, 0xF, true));
}
__device__ __forceinline__ float row_sum16(float x) {
    x += dpp_mov<0xB1>(x);    // quad_perm d^1
    x += dpp_mov<0x4E>(x);    // quad_perm d^2
    x += dpp_mov<0x124>(x);   // row_ror:4
    x += dpp_mov<0x128>(x);   // row_ror:8
    return x;
}

// ========== Kernel A: u_hat (f32) + uniform pass0, LDS-staged ==========
// 8 waves; wave bq handles b=bq*4..bq*4+3. Lane: cq=lane>>4, d=lane&15; c=cq+4r.
// LDS W per n-plane: row R=c*16+d holds W[n,c,:,d] (2 float4 units h) at
// swizzled unit U=(2R+h)^((R>>2)&7).
__global__ __launch_bounds__(TPB) void caps_uhat_pass0(
    const float* __restrict__ xg,
    const float* __restrict__ Wg,
    float* __restrict__ uhat,          // [B,N,C*D]
    float* __restrict__ part)          // [GA][SOUT]
{
    __shared__ float Wl[NCHUNK_A * CC * DIN * DD];  // 20KB, swizzled [j][R][i]

    const int t    = threadIdx.x;
    const int lane = t & 63;
    const int bqu  = __builtin_amdgcn_readfirstlane(t >> 6);
    const int cq   = lane >> 4;
    const int d    = lane & 15;
    const int n0   = blockIdx.x * NCHUNK_A;

    float acc[4][3];
    #pragma unroll
    for (int bb = 0; bb < 4; ++bb)
        #pragma unroll
        for (int r = 0; r < 3; ++r) acc[bb][r] = 0.f;

    // stage W for 4 planes (1280 float4), transposed + swizzled
    {
        const float4* WgV = (const float4*)Wg;
        #pragma unroll
        for (int wi = 0; wi < 3; ++wi) {
            int m4 = t + wi * TPB;              // 0..1535
            if (m4 < NCHUNK_A * 320) {
                int j  = m4 / 320;
                int q  = m4 - j * 320;
                int c  = q >> 5, i = (q & 31) >> 2, d0 = (q & 3) << 2;
                float4 v = WgV[(size_t)n0 * 320 + m4];
                const float* vf = (const float*)&v;
                float* plane = Wl + j * 1280;
                int h = i >> 2, wd = i & 3;
                #pragma unroll
                for (int k = 0; k < 4; ++k) {
                    int R = c * DD + d0 + k;
                    int U = (R * 2 + h) ^ ((R >> 2) & 7);
                    plane[U * 4 + wd] = vf[k];
                }
            }
        }
    }
    __syncthreads();

    #pragma unroll 1   // prevent unroll -> register blowup (r11)
    for (int j = 0; j < NCHUNK_A; ++j) {
        const float4* planeV = (const float4*)(Wl + j * 1280);
        const int n = n0 + j;

        // u rows: wave-uniform -> scalar loads
        float ub[4][8];
        #pragma unroll
        for (int bb = 0; bb < 4; ++bb) {
            const float* up = xg + ((size_t)(bqu * 4 + bb) * NN + n) * DIN;
            #pragma unroll
            for (int i = 0; i < 8; ++i) ub[bb][i] = up[i];
        }

        #pragma unroll
        for (int r = 0; r < 3; ++r) {
            const int c = cq + 4 * r;
            float w0=0,w1=0,w2=0,w3=0,w4=0,w5=0,w6=0,w7=0;
            if (c < CC) {
                int R  = c * DD + d;
                int sw = (R >> 2) & 7;
                float4 a0 = planeV[(R * 2) ^ sw];
                float4 a1 = planeV[(R * 2 + 1) ^ sw];
                w0=a0.x; w1=a0.y; w2=a0.z; w3=a0.w;
                w4=a1.x; w5=a1.y; w6=a1.z; w7=a1.w;
            }
            #pragma unroll
            for (int bb = 0; bb < 4; ++bb) {
                const int b = bqu * 4 + bb;
                float s = 0.f;
                s = fmaf(ub[bb][0], w0, s); s = fmaf(ub[bb][1], w1, s);
                s = fmaf(ub[bb][2], w2, s); s = fmaf(ub[bb][3], w3, s);
                s = fmaf(ub[bb][4], w4, s); s = fmaf(ub[bb][5], w5, s);
                s = fmaf(ub[bb][6], w6, s); s = fmaf(ub[bb][7], w7, s);
                if (c < CC)
                    uhat[((size_t)b * NN + n) * (CC * DD) + lane + 64 * r] = s;
                acc[bb][r] += s;
            }
        }
    }

    float* dst = part + (size_t)blockIdx.x * SOUT;
    #pragma unroll
    for (int bb = 0; bb < 4; ++bb) {
        int b = bqu * 4 + bb;
        #pragma unroll
        for (int r = 0; r < 3; ++r) {
            int c = cq + 4 * r;
            if (c < CC) dst[(b * CC + c) * DD + d] = acc[bb][r] * (1.0f / CC);
        }
    }
}

// ========== Kernel B: routed pass streaming f32 u_hat (no LDS) ==========
__global__ __launch_bounds__(TPB) void caps_routed(
    const float* __restrict__ uhat,    // [B,N,C*D]
    const float* __restrict__ vprev,   // [B,C,D]
    float* __restrict__ part)          // [GB][SOUT]
{
    const int t    = threadIdx.x;
    const int lane = t & 63;
    const int bqu  = __builtin_amdgcn_readfirstlane(t >> 6);
    const int cq   = lane >> 4;
    const int d    = lane & 15;

    float vv[4][3];
    #pragma unroll
    for (int bb = 0; bb < 4; ++bb) {
        int b = bqu * 4 + bb;
        #pragma unroll
        for (int r = 0; r < 3; ++r) {
            int c = cq + 4 * r;
            vv[bb][r] = (c < CC) ? vprev[(b * CC + c) * DD + d] : 0.f;
        }
    }

    float acc[4][3];
    #pragma unroll
    for (int bb = 0; bb < 4; ++bb)
        #pragma unroll
        for (int r = 0; r < 3; ++r) acc[bb][r] = 0.f;

    const int n0 = blockIdx.x * NCHUNK_B;

    #pragma unroll 1
    for (int j = 0; j < NCHUNK_B; ++j) {
        const int n = n0 + j;
        float uh[4][3];
        #pragma unroll
        for (int bb = 0; bb < 4; ++bb) {
            const float* base =
                uhat + ((size_t)(bqu * 4 + bb) * NN + n) * (CC * DD);
            #pragma unroll
            for (int r = 0; r < 3; ++r) {
                int c = cq + 4 * r;
                uh[bb][r] = (c < CC) ? base[lane + 64 * r] : 0.f;  // coalesced
            }
        }
        #pragma unroll
        for (int bb = 0; bb < 4; ++bb) {
            float dot0 = row_sum16(uh[bb][0] * vv[bb][0]);
            float dot1 = row_sum16(uh[bb][1] * vv[bb][1]);
            float dot2 = row_sum16(uh[bb][2] * vv[bb][2]);
            // no max-subtract: |dot| bounded (~2), exp safe (r12-verified)
            float e0 = __expf(dot0);
            float e1 = __expf(dot1);
            float e2 = (cq < 2) ? __expf(dot2) : 0.f;
            float den = e0 + e1 + e2;
            den += __shfl_xor(den, 16, 64);
            den += __shfl_xor(den, 32, 64);
            float inv = __builtin_amdgcn_rcpf(den);
            acc[bb][0] = fmaf(e0 * inv, uh[bb][0], acc[bb][0]);
            acc[bb][1] = fmaf(e1 * inv, uh[bb][1], acc[bb][1]);
            acc[bb][2] = fmaf(e2 * inv, uh[bb][2], acc[bb][2]);
        }
    }

    float* dst = part + (size_t)blockIdx.x * SOUT;
    #pragma unroll
    for (int bb = 0; bb < 4; ++bb) {
        int b = bqu * 4 + bb;
        #pragma unroll
        for (int r = 0; r < 3; ++r) {
            int c = cq + 4 * r;
            if (c < CC) dst[(b * CC + c) * DD + d] = acc[bb][r];
        }
    }
}

// ===== Fused cross-block reduce + squash, TPB=1024, any G (stride-64) =====
// MODE 0: vsum=v ; 1: vsum+=v ; 2: outF=v
template<int MODE>
__global__ __launch_bounds__(1024) void caps_reduce(
    const float* __restrict__ part,   // [G][SOUT]
    int G,
    float* __restrict__ vsum,
    float* __restrict__ outF)
{
    __shared__ float red[1024];
    const int row = blockIdx.x;       // b*CC + c
    const int t = threadIdx.x;
    const int d = t & 15, ks = t >> 4;             // 64 k-slices
    const float* p = part + row * DD + d;
    float s = 0.f;
    for (int s_i = ks; s_i < G; s_i += 64)
        s += p[(size_t)s_i * SOUT];
    red[t] = s;
    __syncthreads();
    if (t < 16) {
        float sd = 0.f;
        #pragma unroll
        for (int k2 = 0; k2 < 64; ++k2) sd += red[k2 * 16 + t];
        float s2 = sd * sd;
        #pragma unroll
        for (int m = 1; m < 16; m <<= 1) s2 += __shfl_xor(s2, m, 64);
        float f = s2 / ((1.f + s2) * sqrtf(s2 + 1e-7f));
        float v = f * sd;
        int idx = row * DD + t;
        if (MODE == 0) vsum[idx] = v;
        if (MODE == 1) vsum[idx] += v;
        if (MODE == 2) outF[idx] = v;
    }
}

// ======== Fallback (r14-proven): LDS recompute pass, grid-stride ========
template<int UNIFORM, int PARTIALS>
__global__ __launch_bounds__(TPB) void caps_pass(
    const float* __restrict__ xg,
    const float* __restrict__ Wg,
    const float* __restrict__ vprev,
    float* __restrict__ outp)
{
    __shared__ float Wl[NCHUNK_B * CC * DIN * DD];

    const int t    = threadIdx.x;
    const int lane = t & 63;
    const int bqu  = __builtin_amdgcn_readfirstlane(t >> 6);
    const int cq   = lane >> 4;
    const int d    = lane & 15;

    float vv[4][3];
    if (!UNIFORM) {
        #pragma unroll
        for (int bb = 0; bb < 4; ++bb) {
            int b = bqu * 4 + bb;
            #pragma unroll
            for (int r = 0; r < 3; ++r) {
                int c = cq + 4 * r;
                vv[bb][r] = (c < CC) ? vprev[(b * CC + c) * DD + d] : 0.f;
            }
        }
    }

    float acc[4][3];
    #pragma unroll
    for (int bb = 0; bb < 4; ++bb)
        #pragma unroll
        for (int r = 0; r < 3; ++r) acc[bb][r] = 0.f;

    for (int chunk = blockIdx.x; chunk < GB; chunk += gridDim.x) {
        const int n0 = chunk * NCHUNK_B;
        {
            const float4* WgV = (const float4*)Wg;
            #pragma unroll
            for (int wi = 0; wi < 5; ++wi) {
                int m4 = t + wi * TPB;
                int j = m4 / 320, q = m4 - j * 320;
                int c = q >> 5, i = (q & 31) >> 2, d0 = (q & 3) << 2;
                float4 v = WgV[(size_t)n0 * 320 + m4];
                const float* vf = (const float*)&v;
                float* plane = Wl + j * 1280;
                int h = i >> 2, wd = i & 3;
                #pragma unroll
                for (int k = 0; k < 4; ++k) {
                    int R = c * DD + d0 + k;
                    int U = (R * 2 + h) ^ ((R >> 2) & 7);
                    plane[U * 4 + wd] = vf[k];
                }
            }
        }
        __syncthreads();

        #pragma unroll 1
        for (int j = 0; j < NCHUNK_B; ++j) {
            const float4* planeV = (const float4*)(Wl + j * 1280);
            float ub[4][8];
            #pragma unroll
            for (int bb = 0; bb < 4; ++bb) {
                const float* up = xg + ((size_t)(bqu * 4 + bb) * NN + n0 + j) * DIN;
                #pragma unroll
                for (int i = 0; i < 8; ++i) ub[bb][i] = up[i];
            }
            float uh[4][3];
            #pragma unroll
            for (int r = 0; r < 3; ++r) {
                int c = cq + 4 * r;
                float w0=0,w1=0,w2=0,w3=0,w4=0,w5=0,w6=0,w7=0;
                if (c < CC) {
                    int R = c * DD + d, sw = (R >> 2) & 7;
                    float4 a0 = planeV[(R * 2) ^ sw];
                    float4 a1 = planeV[(R * 2 + 1) ^ sw];
                    w0=a0.x; w1=a0.y; w2=a0.z; w3=a0.w;
                    w4=a1.x; w5=a1.y; w6=a1.z; w7=a1.w;
                }
                #pragma unroll
                for (int bb = 0; bb < 4; ++bb) {
                    float s = 0.f;
                    s = fmaf(ub[bb][0], w0, s); s = fmaf(ub[bb][1], w1, s);
                    s = fmaf(ub[bb][2], w2, s); s = fmaf(ub[bb][3], w3, s);
                    s = fmaf(ub[bb][4], w4, s); s = fmaf(ub[bb][5], w5, s);
                    s = fmaf(ub[bb][6], w6, s); s = fmaf(ub[bb][7], w7, s);
                    uh[bb][r] = s;
                }
            }
            #pragma unroll
            for (int bb = 0; bb < 4; ++bb) {
                float w0, w1, w2;
                if (UNIFORM) { w0 = w1 = w2 = 1.0f / CC; }
                else {
                    float dot0 = row_sum16(uh[bb][0] * vv[bb][0]);
                    float dot1 = row_sum16(uh[bb][1] * vv[bb][1]);
                    float dot2 = row_sum16(uh[bb][2] * vv[bb][2]);
                    float e0 = __expf(dot0), e1 = __expf(dot1);
                    float e2 = (cq < 2) ? __expf(dot2) : 0.f;
                    float den = e0 + e1 + e2;
                    den += __shfl_xor(den, 16, 64);
                    den += __shfl_xor(den, 32, 64);
                    float inv = __builtin_amdgcn_rcpf(den);
                    w0 = e0 * inv; w1 = e1 * inv; w2 = e2 * inv;
                }
                acc[bb][0] = fmaf(w0, uh[bb][0], acc[bb][0]);
                acc[bb][1] = fmaf(w1, uh[bb][1], acc[bb][1]);
                acc[bb][2] = fmaf(w2, uh[bb][2], acc[bb][2]);
            }
        }
        __syncthreads();
    }

    #pragma unroll
    for (int bb = 0; bb < 4; ++bb) {
        int b = bqu * 4 + bb;
        #pragma unroll
        for (int r = 0; r < 3; ++r) {
            int c = cq + 4 * r;
            if (c < CC) {
                if (PARTIALS) (outp + (size_t)blockIdx.x * SOUT)[(b * CC + c) * DD + d] = acc[bb][r];
                else atomicAdd(&outp[(b * CC + c) * DD + d], acc[bb][r]);
            }
        }
    }
}

// Atomic-fallback squash.
template<int MODE>
__global__ __launch_bounds__(512) void caps_squash(
    const float* __restrict__ sIn, float* __restrict__ vsum,
    float* __restrict__ outF)
{
    int r = blockIdx.x * blockDim.x + threadIdx.x;
    if (r >= BB * CC) return;
    const float* p = sIn + (size_t)r * DD;
    float sv[DD]; float s2 = 0.f;
    #pragma unroll
    for (int d = 0; d < DD; ++d) { sv[d] = p[d]; s2 = fmaf(sv[d], sv[d], s2); }
    float f = s2 / ((1.f + s2) * sqrtf(s2 + 1e-7f));
    #pragma unroll
    for (int d = 0; d < DD; ++d) {
        float v = f * sv[d];
        int idx = r * DD + d;
        if (MODE == 0) vsum[idx] = v;
        if (MODE == 1) vsum[idx] += v;
        if (MODE == 2) outF[idx] = v;
    }
}

extern "C" void kernel_launch(void* const* d_in, const int* in_sizes, int n_in,
                              void* d_out, int out_size, void* d_ws, size_t ws_size,
                              hipStream_t stream) {
    const float* x; const float* Wt;
    if (in_sizes[0] == BB * NN * DIN) { x = (const float*)d_in[0]; Wt = (const float*)d_in[1]; }
    else                              { Wt = (const float*)d_in[0]; x = (const float*)d_in[1]; }
    float* out = (float*)d_out;
    float* ws = (float*)d_ws;

    const size_t need = (UHATF + (size_t)GA * SOUT + SOUT) * sizeof(float);

    if (ws_size >= need) {
        float* uhat = ws;
        float* part = ws + UHATF;              // [GA][SOUT]; B uses first GB slices
        float* vsum = part + (size_t)GA * SOUT;
        caps_uhat_pass0<<<GA, TPB, 0, stream>>>(x, Wt, uhat, part);
        caps_reduce<0><<<BB*CC, 1024, 0, stream>>>(part, GA, vsum, nullptr);
        caps_routed<<<GB, TPB, 0, stream>>>(uhat, vsum, part);
        caps_reduce<1><<<BB*CC, 1024, 0, stream>>>(part, GB, vsum, nullptr);
        caps_routed<<<GB, TPB, 0, stream>>>(uhat, vsum, part);
        caps_reduce<2><<<BB*CC, 1024, 0, stream>>>(part, GB, vsum, out);
    } else {
        // r14-proven fallback
        const size_t wsf = ws_size / sizeof(float);
        int Gf = 0;
        const int cands[5] = {512, 256, 128, 64, 32};
        for (int ci = 0; ci < 5; ++ci)
            if (wsf >= (size_t)(cands[ci] + 1) * SOUT) { Gf = cands[ci]; break; }
        if (Gf > 0) {
            float* part = ws;
            float* vsum = ws + (size_t)Gf * SOUT;
            caps_pass<1,1><<<Gf, TPB, 0, stream>>>(x, Wt, nullptr, part);
            caps_reduce<0><<<BB*CC, 1024, 0, stream>>>(part, Gf, vsum, nullptr);
            caps_pass<0,1><<<Gf, TPB, 0, stream>>>(x, Wt, vsum, part);
            caps_reduce<1><<<BB*CC, 1024, 0, stream>>>(part, Gf, vsum, nullptr);
            caps_pass<0,1><<<Gf, TPB, 0, stream>>>(x, Wt, vsum, part);
            caps_reduce<2><<<BB*CC, 1024, 0, stream>>>(part, Gf, vsum, out);
        } else {
            float* sAcc = ws;
            float* vsum = ws + SOUT;
            hipMemsetAsync(sAcc, 0, SOUT * sizeof(float), stream);
            caps_pass<1,0><<<64, TPB, 0, stream>>>(x, Wt, nullptr, sAcc);
            caps_squash<0><<<1, 512, 0, stream>>>(sAcc, vsum, nullptr);
            hipMemsetAsync(sAcc, 0, SOUT * sizeof(float), stream);
            caps_pass<0,0><<<64, TPB, 0, stream>>>(x, Wt, vsum, sAcc);
            caps_squash<1><<<1, 512, 0, stream>>>(sAcc, vsum, nullptr);
            hipMemsetAsync(sAcc, 0, SOUT * sizeof(float), stream);
            caps_pass<0,0><<<64, TPB, 0, stream>>>(x, Wt, vsum, sAcc);
            caps_squash<2><<<1, 512, 0, stream>>>(sAcc, nullptr, out);
        }
    }
}

// Round 19
// 76.879 us; speedup vs baseline: 1.2163x; 1.0536x over previous
//
#include <hip/hip_runtime.h>
#include <hip/hip_bf16.h>

// CapsNet dynamic routing — v13: v12 structure + bf16 u_hat (halve L3 writes).
// x: [B=32, N=4096, Din=8], W: [N=4096, C=10, Din=8, D=16], out: [B,C,D] f32.
// Algebra (b0=0): iter0 w=1/C; iter1 logits=u_hat.v0; iter2 logits=u_hat.(v0+v1).
// r18 evidence: A steady-state = 46us at only 15MB HBM (L3 absorbs u_hat) ->
// L3 WRITE bandwidth ~2.3TB/s is A's wall (B reads same buffer at 5.2TB/s).
// Fix: u_hat in bf16 (105->52MB written). Numerics proven r17 (absmax 3.9e-3).
// A reverts to r16's better shape: NCHUNK=8, G=512, LDS-staged.

#define BB 32
#define NN 4096
#define CC 10
#define DIN 8
#define DD 16
#define TPB 512
#define SOUT (BB * CC * DD)           // 5120
#define UHATE ((size_t)BB * NN * CC * DD)   // 20,971,520 bf16 elements (42MB)

#define NCHUNK_A 8
#define GA (NN / NCHUNK_A)            // 512
#define NCHUNK_B 8
#define GB (NN / NCHUNK_B)            // 512

// ---- DPP row-of-16 sum (d-reduce), all lanes get the total ----
template<int CTRL>
__device__ __forceinline__ float dpp_mov(float x) {
    return __int_as_float(__builtin_amdgcn_update_dpp(
        0, __float_as_int(x), CTRL, 0xF, 0xF, true));
}
__device__ __forceinline__ float row_sum16(float x) {
    x += dpp_mov<0xB1>(x);    // quad_perm d^1
    x += dpp_mov<0x4E>(x);    // quad_perm d^2
    x += dpp_mov<0x124>(x);   // row_ror:4
    x += dpp_mov<0x128>(x);   // row_ror:8
    return x;
}

// ========== Kernel A: u_hat (bf16) + uniform pass0, LDS-staged ==========
// 8 waves; wave bq handles b=bq*4..bq*4+3. Lane: cq=lane>>4, d=lane&15; c=cq+4r.
// LDS W per n-plane: row R=c*16+d holds W[n,c,:,d] (2 float4 units h) at
// swizzled unit U=(2R+h)^((R>>2)&7).
__global__ __launch_bounds__(TPB) void caps_uhat_pass0(
    const float* __restrict__ xg,
    const float* __restrict__ Wg,
    __hip_bfloat16* __restrict__ uhat, // [B,N,C*D] bf16
    float* __restrict__ part)          // [GA][SOUT]
{
    __shared__ float Wl[NCHUNK_A * CC * DIN * DD];  // 40KB, swizzled [j][R][i]

    const int t    = threadIdx.x;
    const int lane = t & 63;
    const int bqu  = __builtin_amdgcn_readfirstlane(t >> 6);
    const int cq   = lane >> 4;
    const int d    = lane & 15;
    const int n0   = blockIdx.x * NCHUNK_A;

    float acc[4][3];
    #pragma unroll
    for (int bb = 0; bb < 4; ++bb)
        #pragma unroll
        for (int r = 0; r < 3; ++r) acc[bb][r] = 0.f;

    // stage W for 8 planes (2560 float4), transposed + swizzled
    {
        const float4* WgV = (const float4*)Wg;
        #pragma unroll
        for (int wi = 0; wi < 5; ++wi) {
            int m4 = t + wi * TPB;              // 0..2559
            int j  = m4 / 320;
            int q  = m4 - j * 320;
            int c  = q >> 5, i = (q & 31) >> 2, d0 = (q & 3) << 2;
            float4 v = WgV[(size_t)n0 * 320 + m4];
            const float* vf = (const float*)&v;
            float* plane = Wl + j * 1280;
            int h = i >> 2, wd = i & 3;
            #pragma unroll
            for (int k = 0; k < 4; ++k) {
                int R = c * DD + d0 + k;
                int U = (R * 2 + h) ^ ((R >> 2) & 7);
                plane[U * 4 + wd] = vf[k];
            }
        }
    }
    __syncthreads();

    #pragma unroll 1   // prevent unroll -> register blowup (r11)
    for (int j = 0; j < NCHUNK_A; ++j) {
        const float4* planeV = (const float4*)(Wl + j * 1280);
        const int n = n0 + j;

        // u rows: wave-uniform -> scalar loads
        float ub[4][8];
        #pragma unroll
        for (int bb = 0; bb < 4; ++bb) {
            const float* up = xg + ((size_t)(bqu * 4 + bb) * NN + n) * DIN;
            #pragma unroll
            for (int i = 0; i < 8; ++i) ub[bb][i] = up[i];
        }

        #pragma unroll
        for (int r = 0; r < 3; ++r) {
            const int c = cq + 4 * r;
            float w0=0,w1=0,w2=0,w3=0,w4=0,w5=0,w6=0,w7=0;
            if (c < CC) {
                int R  = c * DD + d;
                int sw = (R >> 2) & 7;
                float4 a0 = planeV[(R * 2) ^ sw];
                float4 a1 = planeV[(R * 2 + 1) ^ sw];
                w0=a0.x; w1=a0.y; w2=a0.z; w3=a0.w;
                w4=a1.x; w5=a1.y; w6=a1.z; w7=a1.w;
            }
            #pragma unroll
            for (int bb = 0; bb < 4; ++bb) {
                const int b = bqu * 4 + bb;
                float s = 0.f;
                s = fmaf(ub[bb][0], w0, s); s = fmaf(ub[bb][1], w1, s);
                s = fmaf(ub[bb][2], w2, s); s = fmaf(ub[bb][3], w3, s);
                s = fmaf(ub[bb][4], w4, s); s = fmaf(ub[bb][5], w5, s);
                s = fmaf(ub[bb][6], w6, s); s = fmaf(ub[bb][7], w7, s);
                if (c < CC)
                    uhat[((size_t)b * NN + n) * (CC * DD) + lane + 64 * r] =
                        __float2bfloat16(s);
                acc[bb][r] += s;
            }
        }
    }

    float* dst = part + (size_t)blockIdx.x * SOUT;
    #pragma unroll
    for (int bb = 0; bb < 4; ++bb) {
        int b = bqu * 4 + bb;
        #pragma unroll
        for (int r = 0; r < 3; ++r) {
            int c = cq + 4 * r;
            if (c < CC) dst[(b * CC + c) * DD + d] = acc[bb][r] * (1.0f / CC);
        }
    }
}

// ========== Kernel B: routed pass streaming bf16 u_hat (no LDS) ==========
__global__ __launch_bounds__(TPB) void caps_routed(
    const __hip_bfloat16* __restrict__ uhat,  // [B,N,C*D] bf16
    const float* __restrict__ vprev,          // [B,C,D]
    float* __restrict__ part)                 // [GB][SOUT]
{
    const int t    = threadIdx.x;
    const int lane = t & 63;
    const int bqu  = __builtin_amdgcn_readfirstlane(t >> 6);
    const int cq   = lane >> 4;
    const int d    = lane & 15;

    float vv[4][3];
    #pragma unroll
    for (int bb = 0; bb < 4; ++bb) {
        int b = bqu * 4 + bb;
        #pragma unroll
        for (int r = 0; r < 3; ++r) {
            int c = cq + 4 * r;
            vv[bb][r] = (c < CC) ? vprev[(b * CC + c) * DD + d] : 0.f;
        }
    }

    float acc[4][3];
    #pragma unroll
    for (int bb = 0; bb < 4; ++bb)
        #pragma unroll
        for (int r = 0; r < 3; ++r) acc[bb][r] = 0.f;

    const int n0 = blockIdx.x * NCHUNK_B;

    #pragma unroll 1
    for (int j = 0; j < NCHUNK_B; ++j) {
        const int n = n0 + j;
        float uh[4][3];
        #pragma unroll
        for (int bb = 0; bb < 4; ++bb) {
            const __hip_bfloat16* base =
                uhat + ((size_t)(bqu * 4 + bb) * NN + n) * (CC * DD);
            #pragma unroll
            for (int r = 0; r < 3; ++r) {
                int c = cq + 4 * r;
                uh[bb][r] = (c < CC) ? __bfloat162float(base[lane + 64 * r]) : 0.f;
            }
        }
        #pragma unroll
        for (int bb = 0; bb < 4; ++bb) {
            float dot0 = row_sum16(uh[bb][0] * vv[bb][0]);
            float dot1 = row_sum16(uh[bb][1] * vv[bb][1]);
            float dot2 = row_sum16(uh[bb][2] * vv[bb][2]);
            // no max-subtract: |dot| bounded (~2), exp safe (r12-verified)
            float e0 = __expf(dot0);
            float e1 = __expf(dot1);
            float e2 = (cq < 2) ? __expf(dot2) : 0.f;
            float den = e0 + e1 + e2;
            den += __shfl_xor(den, 16, 64);
            den += __shfl_xor(den, 32, 64);
            float inv = __builtin_amdgcn_rcpf(den);
            acc[bb][0] = fmaf(e0 * inv, uh[bb][0], acc[bb][0]);
            acc[bb][1] = fmaf(e1 * inv, uh[bb][1], acc[bb][1]);
            acc[bb][2] = fmaf(e2 * inv, uh[bb][2], acc[bb][2]);
        }
    }

    float* dst = part + (size_t)blockIdx.x * SOUT;
    #pragma unroll
    for (int bb = 0; bb < 4; ++bb) {
        int b = bqu * 4 + bb;
        #pragma unroll
        for (int r = 0; r < 3; ++r) {
            int c = cq + 4 * r;
            if (c < CC) dst[(b * CC + c) * DD + d] = acc[bb][r];
        }
    }
}

// ===== Fused cross-block reduce + squash, TPB=1024, any G (stride-64) =====
// MODE 0: vsum=v ; 1: vsum+=v ; 2: outF=v
template<int MODE>
__global__ __launch_bounds__(1024) void caps_reduce(
    const float* __restrict__ part,   // [G][SOUT]
    int G,
    float* __restrict__ vsum,
    float* __restrict__ outF)
{
    __shared__ float red[1024];
    const int row = blockIdx.x;       // b*CC + c
    const int t = threadIdx.x;
    const int d = t & 15, ks = t >> 4;             // 64 k-slices
    const float* p = part + row * DD + d;
    float s = 0.f;
    for (int s_i = ks; s_i < G; s_i += 64)
        s += p[(size_t)s_i * SOUT];
    red[t] = s;
    __syncthreads();
    if (t < 16) {
        float sd = 0.f;
        #pragma unroll
        for (int k2 = 0; k2 < 64; ++k2) sd += red[k2 * 16 + t];
        float s2 = sd * sd;
        #pragma unroll
        for (int m = 1; m < 16; m <<= 1) s2 += __shfl_xor(s2, m, 64);
        float f = s2 / ((1.f + s2) * sqrtf(s2 + 1e-7f));
        float v = f * sd;
        int idx = row * DD + t;
        if (MODE == 0) vsum[idx] = v;
        if (MODE == 1) vsum[idx] += v;
        if (MODE == 2) outF[idx] = v;
    }
}

// ======== Fallback (r14-proven): LDS recompute pass, grid-stride ========
template<int UNIFORM, int PARTIALS>
__global__ __launch_bounds__(TPB) void caps_pass(
    const float* __restrict__ xg,
    const float* __restrict__ Wg,
    const float* __restrict__ vprev,
    float* __restrict__ outp)
{
    __shared__ float Wl[NCHUNK_B * CC * DIN * DD];

    const int t    = threadIdx.x;
    const int lane = t & 63;
    const int bqu  = __builtin_amdgcn_readfirstlane(t >> 6);
    const int cq   = lane >> 4;
    const int d    = lane & 15;

    float vv[4][3];
    if (!UNIFORM) {
        #pragma unroll
        for (int bb = 0; bb < 4; ++bb) {
            int b = bqu * 4 + bb;
            #pragma unroll
            for (int r = 0; r < 3; ++r) {
                int c = cq + 4 * r;
                vv[bb][r] = (c < CC) ? vprev[(b * CC + c) * DD + d] : 0.f;
            }
        }
    }

    float acc[4][3];
    #pragma unroll
    for (int bb = 0; bb < 4; ++bb)
        #pragma unroll
        for (int r = 0; r < 3; ++r) acc[bb][r] = 0.f;

    for (int chunk = blockIdx.x; chunk < GB; chunk += gridDim.x) {
        const int n0 = chunk * NCHUNK_B;
        {
            const float4* WgV = (const float4*)Wg;
            #pragma unroll
            for (int wi = 0; wi < 5; ++wi) {
                int m4 = t + wi * TPB;
                int j = m4 / 320, q = m4 - j * 320;
                int c = q >> 5, i = (q & 31) >> 2, d0 = (q & 3) << 2;
                float4 v = WgV[(size_t)n0 * 320 + m4];
                const float* vf = (const float*)&v;
                float* plane = Wl + j * 1280;
                int h = i >> 2, wd = i & 3;
                #pragma unroll
                for (int k = 0; k < 4; ++k) {
                    int R = c * DD + d0 + k;
                    int U = (R * 2 + h) ^ ((R >> 2) & 7);
                    plane[U * 4 + wd] = vf[k];
                }
            }
        }
        __syncthreads();

        #pragma unroll 1
        for (int j = 0; j < NCHUNK_B; ++j) {
            const float4* planeV = (const float4*)(Wl + j * 1280);
            float ub[4][8];
            #pragma unroll
            for (int bb = 0; bb < 4; ++bb) {
                const float* up = xg + ((size_t)(bqu * 4 + bb) * NN + n0 + j) * DIN;
                #pragma unroll
                for (int i = 0; i < 8; ++i) ub[bb][i] = up[i];
            }
            float uh[4][3];
            #pragma unroll
            for (int r = 0; r < 3; ++r) {
                int c = cq + 4 * r;
                float w0=0,w1=0,w2=0,w3=0,w4=0,w5=0,w6=0,w7=0;
                if (c < CC) {
                    int R = c * DD + d, sw = (R >> 2) & 7;
                    float4 a0 = planeV[(R * 2) ^ sw];
                    float4 a1 = planeV[(R * 2 + 1) ^ sw];
                    w0=a0.x; w1=a0.y; w2=a0.z; w3=a0.w;
                    w4=a1.x; w5=a1.y; w6=a1.z; w7=a1.w;
                }
                #pragma unroll
                for (int bb = 0; bb < 4; ++bb) {
                    float s = 0.f;
                    s = fmaf(ub[bb][0], w0, s); s = fmaf(ub[bb][1], w1, s);
                    s = fmaf(ub[bb][2], w2, s); s = fmaf(ub[bb][3], w3, s);
                    s = fmaf(ub[bb][4], w4, s); s = fmaf(ub[bb][5], w5, s);
                    s = fmaf(ub[bb][6], w6, s); s = fmaf(ub[bb][7], w7, s);
                    uh[bb][r] = s;
                }
            }
            #pragma unroll
            for (int bb = 0; bb < 4; ++bb) {
                float w0, w1, w2;
                if (UNIFORM) { w0 = w1 = w2 = 1.0f / CC; }
                else {
                    float dot0 = row_sum16(uh[bb][0] * vv[bb][0]);
                    float dot1 = row_sum16(uh[bb][1] * vv[bb][1]);
                    float dot2 = row_sum16(uh[bb][2] * vv[bb][2]);
                    float e0 = __expf(dot0), e1 = __expf(dot1);
                    float e2 = (cq < 2) ? __expf(dot2) : 0.f;
                    float den = e0 + e1 + e2;
                    den += __shfl_xor(den, 16, 64);
                    den += __shfl_xor(den, 32, 64);
                    float inv = __builtin_amdgcn_rcpf(den);
                    w0 = e0 * inv; w1 = e1 * inv; w2 = e2 * inv;
                }
                acc[bb][0] = fmaf(w0, uh[bb][0], acc[bb][0]);
                acc[bb][1] = fmaf(w1, uh[bb][1], acc[bb][1]);
                acc[bb][2] = fmaf(w2, uh[bb][2], acc[bb][2]);
            }
        }
        __syncthreads();
    }

    #pragma unroll
    for (int bb = 0; bb < 4; ++bb) {
        int b = bqu * 4 + bb;
        #pragma unroll
        for (int r = 0; r < 3; ++r) {
            int c = cq + 4 * r;
            if (c < CC) {
                if (PARTIALS) (outp + (size_t)blockIdx.x * SOUT)[(b * CC + c) * DD + d] = acc[bb][r];
                else atomicAdd(&outp[(b * CC + c) * DD + d], acc[bb][r]);
            }
        }
    }
}

// Atomic-fallback squash.
template<int MODE>
__global__ __launch_bounds__(512) void caps_squash(
    const float* __restrict__ sIn, float* __restrict__ vsum,
    float* __restrict__ outF)
{
    int r = blockIdx.x * blockDim.x + threadIdx.x;
    if (r >= BB * CC) return;
    const float* p = sIn + (size_t)r * DD;
    float sv[DD]; float s2 = 0.f;
    #pragma unroll
    for (int d = 0; d < DD; ++d) { sv[d] = p[d]; s2 = fmaf(sv[d], sv[d], s2); }
    float f = s2 / ((1.f + s2) * sqrtf(s2 + 1e-7f));
    #pragma unroll
    for (int d = 0; d < DD; ++d) {
        float v = f * sv[d];
        int idx = r * DD + d;
        if (MODE == 0) vsum[idx] = v;
        if (MODE == 1) vsum[idx] += v;
        if (MODE == 2) outF[idx] = v;
    }
}

extern "C" void kernel_launch(void* const* d_in, const int* in_sizes, int n_in,
                              void* d_out, int out_size, void* d_ws, size_t ws_size,
                              hipStream_t stream) {
    const float* x; const float* Wt;
    if (in_sizes[0] == BB * NN * DIN) { x = (const float*)d_in[0]; Wt = (const float*)d_in[1]; }
    else                              { Wt = (const float*)d_in[0]; x = (const float*)d_in[1]; }
    float* out = (float*)d_out;
    float* ws = (float*)d_ws;

    const size_t uhat_floats = UHATE / 2;   // bf16 elems in float-slot units
    const size_t need = UHATE * sizeof(__hip_bfloat16)
                      + (size_t)(GA + 1) * SOUT * sizeof(float);

    if (ws_size >= need) {
        __hip_bfloat16* uhat = (__hip_bfloat16*)ws;
        float* part = ws + uhat_floats;        // [GA][SOUT]
        float* vsum = part + (size_t)GA * SOUT;
        caps_uhat_pass0<<<GA, TPB, 0, stream>>>(x, Wt, uhat, part);
        caps_reduce<0><<<BB*CC, 1024, 0, stream>>>(part, GA, vsum, nullptr);
        caps_routed<<<GB, TPB, 0, stream>>>(uhat, vsum, part);
        caps_reduce<1><<<BB*CC, 1024, 0, stream>>>(part, GB, vsum, nullptr);
        caps_routed<<<GB, TPB, 0, stream>>>(uhat, vsum, part);
        caps_reduce<2><<<BB*CC, 1024, 0, stream>>>(part, GB, vsum, out);
    } else {
        // r14-proven fallback
        const size_t wsf = ws_size / sizeof(float);
        int Gf = 0;
        const int cands[5] = {512, 256, 128, 64, 32};
        for (int ci = 0; ci < 5; ++ci)
            if (wsf >= (size_t)(cands[ci] + 1) * SOUT) { Gf = cands[ci]; break; }
        if (Gf > 0) {
            float* part = ws;
            float* vsum = ws + (size_t)Gf * SOUT;
            caps_pass<1,1><<<Gf, TPB, 0, stream>>>(x, Wt, nullptr, part);
            caps_reduce<0><<<BB*CC, 1024, 0, stream>>>(part, Gf, vsum, nullptr);
            caps_pass<0,1><<<Gf, TPB, 0, stream>>>(x, Wt, vsum, part);
            caps_reduce<1><<<BB*CC, 1024, 0, stream>>>(part, Gf, vsum, nullptr);
            caps_pass<0,1><<<Gf, TPB, 0, stream>>>(x, Wt, vsum, part);
            caps_reduce<2><<<BB*CC, 1024, 0, stream>>>(part, Gf, vsum, out);
        } else {
            float* sAcc = ws;
            float* vsum = ws + SOUT;
            hipMemsetAsync(sAcc, 0, SOUT * sizeof(float), stream);
            caps_pass<1,0><<<64, TPB, 0, stream>>>(x, Wt, nullptr, sAcc);
            caps_squash<0><<<1, 512, 0, stream>>>(sAcc, vsum, nullptr);
            hipMemsetAsync(sAcc, 0, SOUT * sizeof(float), stream);
            caps_pass<0,0><<<64, TPB, 0, stream>>>(x, Wt, vsum, sAcc);
            caps_squash<1><<<1, 512, 0, stream>>>(sAcc, vsum, nullptr);
            hipMemsetAsync(sAcc, 0, SOUT * sizeof(float), stream);
            caps_pass<0,0><<<64, TPB, 0, stream>>>(x, Wt, vsum, sAcc);
            caps_squash<2><<<1, 512, 0, stream>>>(sAcc, nullptr, out);
        }
    }
}